// Round 1
// baseline (69.789 us; speedup 1.0000x reference)
//
#include <hip/hip_runtime.h>

// Problem constants (from reference):
//   positions: (8, 256, 256, 2) float32  -> 524288 points
//   embeddings: (64, 64, 128) float32    -> 2 MB table (L2-resident)
//   output: (8, 256, 256, 128) float32   -> 268 MB
#define GX 64
#define GY 64
#define NF 128
#define NPOINTS (8 * 256 * 256)
#define CHUNKS_PER_POINT (NF / 4)   // 32 float4 chunks per point

__global__ __launch_bounds__(256) void bilerp2d_kernel(
    const float* __restrict__ pos,
    const float* __restrict__ emb,
    float* __restrict__ out)
{
    const float4* __restrict__ e4 = reinterpret_cast<const float4*>(emb);
    float4* __restrict__ out4 = reinterpret_cast<float4*>(out);

    const unsigned int total = NPOINTS * CHUNKS_PER_POINT; // 16,777,216
    const unsigned int stride = gridDim.x * blockDim.x;

    for (unsigned int idx = blockIdx.x * blockDim.x + threadIdx.x;
         idx < total; idx += stride) {
        const unsigned int point = idx >> 5;       // /32
        const unsigned int c     = idx & 31;       // float4 chunk within feature dim

        // 32 consecutive lanes share the same point -> these 8B loads
        // broadcast from L1 (same cacheline).
        const float px = pos[point * 2 + 0];
        const float py = pos[point * 2 + 1];

        const float xf = px * (float)GX;   // origin 0, size 1
        const float yf = py * (float)GY;
        const float fx0 = floorf(xf);
        const float fy0 = floorf(yf);
        const int x0 = (int)fx0;
        const int y0 = (int)fy0;
        const float dx = xf - fx0;
        const float dy = yf - fy0;

        const int x0c = min(max(x0, 0), GX - 1);
        const int y0c = min(max(y0, 0), GY - 1);
        const int x1  = min(max(x0 + 1, 0), GX - 1);
        const int y1  = min(max(y0 + 1, 0), GY - 1);

        // Each corner row is 128 f32 = 512 B contiguous; the 32-lane group
        // reads it as 32 x float4 -> fully coalesced, served from L2/L1.
        const float4 f00 = e4[(unsigned)(x0c * GY + y0c) * CHUNKS_PER_POINT + c];
        const float4 f10 = e4[(unsigned)(x1  * GY + y0c) * CHUNKS_PER_POINT + c];
        const float4 f01 = e4[(unsigned)(x0c * GY + y1 ) * CHUNKS_PER_POINT + c];
        const float4 f11 = e4[(unsigned)(x1  * GY + y1 ) * CHUNKS_PER_POINT + c];

        // Match reference blend structure: lerp in x, then in y.
        const float omdx = 1.0f - dx;
        const float omdy = 1.0f - dy;

        float4 r;
        {
            float a, b;
            a = f00.x * omdx + f10.x * dx;
            b = f01.x * omdx + f11.x * dx;
            r.x = a * omdy + b * dy;
            a = f00.y * omdx + f10.y * dx;
            b = f01.y * omdx + f11.y * dx;
            r.y = a * omdy + b * dy;
            a = f00.z * omdx + f10.z * dx;
            b = f01.z * omdx + f11.z * dx;
            r.z = a * omdy + b * dy;
            a = f00.w * omdx + f10.w * dx;
            b = f01.w * omdx + f11.w * dx;
            r.w = a * omdy + b * dy;
        }

        out4[idx] = r; // coalesced 16B/lane store
    }
}

extern "C" void kernel_launch(void* const* d_in, const int* in_sizes, int n_in,
                              void* d_out, int out_size, void* d_ws, size_t ws_size,
                              hipStream_t stream) {
    const float* positions  = (const float*)d_in[0];
    const float* embeddings = (const float*)d_in[1];
    float* out = (float*)d_out;

    const int block = 256;
    const int grid = 2048; // 256 CUs x 8 blocks; grid-stride covers the rest
    bilerp2d_kernel<<<grid, block, 0, stream>>>(positions, embeddings, out);
}

// Round 3
// 58.876 us; speedup vs baseline: 1.1854x; 1.1854x over previous
//
#include <hip/hip_runtime.h>

// positions: (8, 256, 256, 2) float32  -> 524288 points
// embeddings: (64, 64, 128) float32    -> 2 MB table (L2-resident)
// output: (8, 256, 256, 128) float32   -> 268 MB
#define GX 64
#define GY 64
#define NF 128
#define NPOINTS (8 * 256 * 256)
#define C4 (NF / 4)          // 32 float4 chunks per point
#define HALF (C4 / 2)        // 16: each thread does chunk c and c+16

typedef float v4f __attribute__((ext_vector_type(4)));

__device__ __forceinline__ v4f lerp2(const v4f a, const v4f b,
                                     const v4f cc, const v4f d,
                                     float omdx, float dx,
                                     float omdy, float dy) {
    v4f top = a * omdx + b * dx;
    v4f bot = cc * omdx + d * dx;
    return top * omdy + bot * dy;
}

__global__ __launch_bounds__(256) void bilerp2d_kernel(
    const float* __restrict__ pos,
    const float* __restrict__ emb,
    float* __restrict__ out)
{
    const v4f* __restrict__ e4 = reinterpret_cast<const v4f*>(emb);
    v4f* __restrict__ out4 = reinterpret_cast<v4f*>(out);

    const unsigned int total = NPOINTS * HALF;   // 8,388,608 work items
    const unsigned int stride = gridDim.x * blockDim.x;

    for (unsigned int idx = blockIdx.x * blockDim.x + threadIdx.x;
         idx < total; idx += stride) {
        const unsigned int point = idx >> 4;     // 16 lanes per point
        const unsigned int c     = idx & (HALF - 1);

        // 16 consecutive lanes share the point -> broadcast from L1.
        const float px = pos[point * 2 + 0];
        const float py = pos[point * 2 + 1];

        const float xf = px * (float)GX;
        const float yf = py * (float)GY;
        const float fx0 = floorf(xf);
        const float fy0 = floorf(yf);
        const int x0 = (int)fx0;
        const int y0 = (int)fy0;
        const float dx = xf - fx0;
        const float dy = yf - fy0;

        const int x0c = min(max(x0, 0), GX - 1);
        const int y0c = min(max(y0, 0), GY - 1);
        const int x1  = min(max(x0 + 1, 0), GX - 1);
        const int y1  = min(max(y0 + 1, 0), GY - 1);

        const unsigned b00 = (unsigned)(x0c * GY + y0c) * C4;
        const unsigned b10 = (unsigned)(x1  * GY + y0c) * C4;
        const unsigned b01 = (unsigned)(x0c * GY + y1 ) * C4;
        const unsigned b11 = (unsigned)(x1  * GY + y1 ) * C4;

        // 8 independent gathers (two feature chunks per corner) -> deep MLP.
        const v4f f00a = e4[b00 + c];
        const v4f f10a = e4[b10 + c];
        const v4f f01a = e4[b01 + c];
        const v4f f11a = e4[b11 + c];
        const v4f f00b = e4[b00 + c + HALF];
        const v4f f10b = e4[b10 + c + HALF];
        const v4f f01b = e4[b01 + c + HALF];
        const v4f f11b = e4[b11 + c + HALF];

        const float omdx = 1.0f - dx;
        const float omdy = 1.0f - dy;

        const v4f ra = lerp2(f00a, f10a, f01a, f11a, omdx, dx, omdy, dy);
        const v4f rb = lerp2(f00b, f10b, f01b, f11b, omdx, dx, omdy, dy);

        // Nontemporal: don't let the 268 MB output stream thrash L2.
        const unsigned obase = point * C4 + c;
        __builtin_nontemporal_store(ra, &out4[obase]);
        __builtin_nontemporal_store(rb, &out4[obase + HALF]);
    }
}

extern "C" void kernel_launch(void* const* d_in, const int* in_sizes, int n_in,
                              void* d_out, int out_size, void* d_ws, size_t ws_size,
                              hipStream_t stream) {
    const float* positions  = (const float*)d_in[0];
    const float* embeddings = (const float*)d_in[1];
    float* out = (float*)d_out;

    const int block = 256;
    const int grid = 4096; // 8 grid-stride iterations per thread
    bilerp2d_kernel<<<grid, block, 0, stream>>>(positions, embeddings, out);
}

// Round 4
// 57.683 us; speedup vs baseline: 1.2099x; 1.0207x over previous
//
#include <hip/hip_runtime.h>

// positions: (8, 256, 256, 2) float32  -> 524288 points
// embeddings: (64, 64, 128) float32    -> 2 MB table (L2-resident)
// output: (8, 256, 256, 128) float32   -> 268 MB
#define GX 64
#define GY 64
#define NF 128
#define NPOINTS (8 * 256 * 256)
#define C4 (NF / 4)          // 32 float4 chunks per point
#define LPP 8                // lanes per point
#define CPT (C4 / LPP)       // 4 chunks per thread

typedef float v4f __attribute__((ext_vector_type(4)));

__device__ __forceinline__ v4f lerp2(const v4f a, const v4f b,
                                     const v4f cc, const v4f d,
                                     float omdx, float dx,
                                     float omdy, float dy) {
    v4f top = a * omdx + b * dx;
    v4f bot = cc * omdx + d * dx;
    return top * omdy + bot * dy;
}

__global__ __launch_bounds__(256) void bilerp2d_kernel(
    const float* __restrict__ pos,
    const float* __restrict__ emb,
    float* __restrict__ out)
{
    const v4f* __restrict__ e4 = reinterpret_cast<const v4f*>(emb);
    v4f* __restrict__ out4 = reinterpret_cast<v4f*>(out);
    const float2* __restrict__ pos2 = reinterpret_cast<const float2*>(pos);

    const unsigned int idx = blockIdx.x * blockDim.x + threadIdx.x;
    const unsigned int point = idx >> 3;          // 8 lanes per point
    const unsigned int c     = idx & (LPP - 1);   // base chunk 0..7

    // 8 consecutive lanes share the point -> broadcast from L1.
    const float2 p = pos2[point];

    const float xf = p.x * (float)GX;
    const float yf = p.y * (float)GY;
    const float fx0 = floorf(xf);
    const float fy0 = floorf(yf);
    const int x0 = (int)fx0;
    const int y0 = (int)fy0;
    const float dx = xf - fx0;
    const float dy = yf - fy0;

    const int x0c = min(max(x0, 0), GX - 1);
    const int y0c = min(max(y0, 0), GY - 1);
    const int x1  = min(max(x0 + 1, 0), GX - 1);
    const int y1  = min(max(y0 + 1, 0), GY - 1);

    const unsigned b00 = (unsigned)(x0c * GY + y0c) * C4 + c;
    const unsigned b10 = (unsigned)(x1  * GY + y0c) * C4 + c;
    const unsigned b01 = (unsigned)(x0c * GY + y1 ) * C4 + c;
    const unsigned b11 = (unsigned)(x1  * GY + y1 ) * C4 + c;

    // 16 independent gathers (4 feature chunks x 4 corners) -> deep MLP.
    v4f f00[CPT], f10[CPT], f01[CPT], f11[CPT];
#pragma unroll
    for (int k = 0; k < CPT; ++k) {
        f00[k] = e4[b00 + k * LPP];
        f10[k] = e4[b10 + k * LPP];
        f01[k] = e4[b01 + k * LPP];
        f11[k] = e4[b11 + k * LPP];
    }

    const float omdx = 1.0f - dx;
    const float omdy = 1.0f - dy;

    const unsigned obase = point * C4 + c;
#pragma unroll
    for (int k = 0; k < CPT; ++k) {
        const v4f r = lerp2(f00[k], f10[k], f01[k], f11[k], omdx, dx, omdy, dy);
        // Nontemporal: don't let the 268 MB output stream thrash L2.
        __builtin_nontemporal_store(r, &out4[obase + k * LPP]);
    }
}

extern "C" void kernel_launch(void* const* d_in, const int* in_sizes, int n_in,
                              void* d_out, int out_size, void* d_ws, size_t ws_size,
                              hipStream_t stream) {
    const float* positions  = (const float*)d_in[0];
    const float* embeddings = (const float*)d_in[1];
    float* out = (float*)d_out;

    const int block = 256;
    // one thread per (point, base-chunk): 524288 * 8 / 256 = 16384 blocks
    const int grid = (NPOINTS * LPP) / block;
    bilerp2d_kernel<<<grid, block, 0, stream>>>(positions, embeddings, out);
}